// Round 4
// baseline (440.249 us; speedup 1.0000x reference)
//
#include <hip/hip_runtime.h>
#include <hip/hip_bf16.h>

#define EPS 1e-6f

constexpr int D  = 160;     // "D" axis (T//S)
constexpr int NN = 82944;   // C*H*W
constexpr int B  = 4;       // batches

typedef __bf16 bf16x8 __attribute__((ext_vector_type(8)));
typedef float  floatx4 __attribute__((ext_vector_type(4)));

// ---------------- Kernel A: partial Gram P[blk] = X_slab X_slab^T (bf16 MFMA) ----
// Async rewrite: global_load_lds width=16 DMA (no VGPR staging, no ds_write),
// f32 LDS slabs [160][64], 2-deep slab pipeline with counted s_waitcnt vmcnt(10)
// and raw s_barrier (T3/T4). LDS layout XOR-swizzled BOTH sides (rule #21):
// lane's global source slot = j ^ (row&7)  (pre-swizzled source, linear DMA dest),
// fragment read uses slot g ^ (row&7) -> conflict-free ds_read_b128.
// f32->bf16 conversion happens at fragment read (VALU is ~8% of slab budget).
constexpr int BK = 64;            // columns per LDS slab (256 B/row)
constexpr int SLABS = 16;         // slabs per block
constexpr int COLS_PER_BLOCK = BK * SLABS;          // 1024
constexpr int GRAM_BLOCKS = NN / COLS_PER_BLOCK;    // 81 (x4 batches = 324 blocks)

#define GLD16(gp, lp)                                                               \
    __builtin_amdgcn_global_load_lds(                                               \
        (const __attribute__((address_space(1))) unsigned int*)(const void*)(gp),   \
        (__attribute__((address_space(3))) unsigned int*)(void*)(lp), 16, 0, 0)

__global__ __launch_bounds__(256, 2)
void gram_kernel(const float* __restrict__ x, float* __restrict__ P)
{
    __shared__ __align__(16) float xs[2][D * BK];   // 2 x 40 KB = 80 KB

    const int tid = threadIdx.x;
    const int batch = blockIdx.y;
    const int w  = tid >> 6;        // wave 0..3
    const int l  = tid & 63;
    const int lr = l & 15;          // row/col within 16-tile
    const int lq = l >> 4;          // quad 0..3
    const int lr7 = lr & 7;
    const int itile0 = (w & 1) * 5; // wave's 5 row-tiles
    const int jtile0 = (w >> 1) * 5;// wave's 5 col-tiles

    // DMA staging geometry: wave w loads rows [w*40, w*40+40) in 10 chunks of
    // 4 rows; lane l covers row_in_chunk = l>>4, 16B slot (l&15).
    // Pre-swizzled global slot: jg = (l&15) ^ (row&7) = (l&15)^(l>>4)^(4*(p&1))
    // (w*40 ≡ 0 mod 8, so row&7 = (l>>4) + 4*(p&1)).
    const int rbase = w * 40 + (l >> 4);
    const int jg0   = (l & 15) ^ (l >> 4);

    const float* xb = x + (size_t)batch * D * NN + (size_t)blockIdx.x * COLS_PER_BLOCK;

    floatx4 acc[5][5] = {};

    #define ISSUE_SLAB(SIDX, BUF) {                                                 \
        const float* gs_ = xb + (size_t)(SIDX) * BK;                                \
        _Pragma("unroll")                                                           \
        for (int p = 0; p < 10; ++p) {                                              \
            const int row_ = rbase + p * 4;                                         \
            const int jg_  = jg0 ^ ((p & 1) << 2);                                  \
            GLD16(gs_ + (size_t)row_ * NN + jg_ * 4,                                \
                  &(BUF)[(w * 40 + p * 4) * BK]);                                   \
        } }

    #define FRAG_LOAD(TILE, F, BUFP) {                                              \
        const float* rp_ = (BUFP) + ((TILE) * 16 + lr) * BK;                         \
        const floatx4 va_ = *(const floatx4*)(rp_ + ((sbase ^ lr7) << 2));           \
        const floatx4 vb_ = *(const floatx4*)(rp_ + (((sbase + 1) ^ lr7) << 2));     \
        bf16x8 f_;                                                                   \
        f_[0] = (__bf16)va_.x; f_[1] = (__bf16)va_.y;                                \
        f_[2] = (__bf16)va_.z; f_[3] = (__bf16)va_.w;                                \
        f_[4] = (__bf16)vb_.x; f_[5] = (__bf16)vb_.y;                                \
        f_[6] = (__bf16)vb_.z; f_[7] = (__bf16)vb_.w;                                \
        F = f_; }

    #define COMPUTE_SLAB(BUF) {                                                     \
        const float* bufp_ = (BUF);                                                  \
        _Pragma("unroll")                                                            \
        for (int kk = 0; kk < 2; ++kk) {                                             \
            const int sbase = kk * 8 + lq * 2;                                       \
            bf16x8 fa[5], fb[5];                                                     \
            _Pragma("unroll")                                                        \
            for (int i = 0; i < 5; ++i) {                                            \
                FRAG_LOAD(itile0 + i, fa[i], bufp_);                                 \
                FRAG_LOAD(jtile0 + i, fb[i], bufp_);                                 \
            }                                                                        \
            _Pragma("unroll")                                                        \
            for (int i = 0; i < 5; ++i)                                              \
                _Pragma("unroll")                                                    \
                for (int j = 0; j < 5; ++j)                                          \
                    acc[i][j] = __builtin_amdgcn_mfma_f32_16x16x32_bf16(             \
                        fa[i], fb[j], acc[i][j], 0, 0, 0);                           \
        } }

    // prologue: slab 0 in flight
    ISSUE_SLAB(0, xs[0]);

    // phase k: issue k+1 (buffer freed by phase k-1's trailing barrier), wait the
    // OLDEST 10 loads (slab k) with counted vmcnt -- k+1's 10 stay in flight --
    // barrier (memory-clobber asm: no compiler hoisting of the ds_reads), compute,
    // trailing barrier frees buf[k&1] for phase k+1's issue of slab k+2.
    #pragma unroll 2
    for (int k = 0; k < SLABS; ++k) {
        float* bufk = xs[k & 1];
        if (k + 1 < SLABS) {
            ISSUE_SLAB(k + 1, xs[(k + 1) & 1]);
            asm volatile("s_waitcnt vmcnt(10)" ::: "memory");
        } else {
            asm volatile("s_waitcnt vmcnt(0)" ::: "memory");
        }
        asm volatile("s_barrier" ::: "memory");
        COMPUTE_SLAB(bufk);
        asm volatile("s_barrier" ::: "memory");
    }
    #undef ISSUE_SLAB
    #undef FRAG_LOAD
    #undef COMPUTE_SLAB

    // epilogue: permuted coalesced layout. flat = w*6400 + (i*5+j)*256 + l*4 + r.
    // Each (i,j) fragment -> one contiguous 1KB NT store per wave.
    float* Pb = P + ((size_t)batch * GRAM_BLOCKS + blockIdx.x) * (size_t)(D * D)
                  + w * 6400 + l * 4;
    #pragma unroll
    for (int i = 0; i < 5; ++i)
        #pragma unroll
        for (int j = 0; j < 5; ++j)
            __builtin_nontemporal_store(acc[i][j], (floatx4*)(Pb + (i * 5 + j) * 256));
}

// ---------------- Kernel A2: G[b] = sum_k P[b][k] (81-way split-K reduce) --------
__global__ __launch_bounds__(256)
void reduce_kernel(const float* __restrict__ P, float* __restrict__ G)
{
    const int batch = blockIdx.y;
    const int f4 = (blockIdx.x * 256 + threadIdx.x) * 4;
    const float* p = P + (size_t)batch * GRAM_BLOCKS * D * D + f4;
    floatx4 s = {0.f, 0.f, 0.f, 0.f};
    #pragma unroll 9     // 81 = 9*9 -> 9 loads (144B) in flight per thread
    for (int k = 0; k < GRAM_BLOCKS; ++k)
        s += __builtin_nontemporal_load((const floatx4*)(p + (size_t)k * D * D));

    // un-permute: flat = w*6400 + t*256 + l*4 + r, t = i*5+j
    const int w   = f4 / 6400;
    const int rem = f4 % 6400;
    const int t   = rem / 256;
    const int q   = rem % 256;
    const int i   = t / 5;
    const int j   = t % 5;
    const int l   = q >> 2;
    const int d1b = (w & 1) * 80 + i * 16 + (l >> 4) * 4;
    const int d2  = (w >> 1) * 80 + j * 16 + (l & 15);
    float* Gb = G + (size_t)batch * D * D;
    #pragma unroll
    for (int r = 0; r < 4; ++r)
        Gb[(size_t)(d1b + r) * D + d2] = s[r];
}

// ---------------- Kernel B: 4-step multiplicative update on G ----------------
__device__ __forceinline__ float block_reduce_bcast(float v, float* red)
{
    #pragma unroll
    for (int off = 32; off > 0; off >>= 1)
        v += __shfl_xor(v, off, 64);
    const int w = threadIdx.x >> 6;
    if ((threadIdx.x & 63) == 0) red[w] = v;
    __syncthreads();
    float s = red[0] + red[1] + red[2] + red[3];
    __syncthreads();
    return s;
}

__global__ __launch_bounds__(256)
void iter_kernel(const float* __restrict__ bases, const float* __restrict__ G,
                 float* __restrict__ bvec, float* __restrict__ svec)
{
    __shared__ float bs[D];
    __shared__ float red[4];
    const int batch = blockIdx.x;
    const int tid = threadIdx.x;
    const float* Gb = G + (size_t)batch * D * D;

    if (tid < D) bs[tid] = bases[batch * D + tid];
    __syncthreads();

    for (int step = 0; step < 4; ++step) {
        float v = (tid < D) ? bs[tid] * bs[tid] : 0.0f;
        const float btb = block_reduce_bcast(v, red);
        const float gamma = btb + EPS;           // exact at step 0 (coef==1); ~1e-6 rel after

        float m = 0.0f;
        if (tid < D) {
            const float* row = Gb + (size_t)tid * D;
            #pragma unroll 8
            for (int j = 0; j < D; j += 4) {
                float4 g4 = *(const float4*)(row + j);
                m += g4.x * bs[j] + g4.y * bs[j + 1] + g4.z * bs[j + 2] + g4.w * bs[j + 3];
            }
        }
        float bm = (tid < D) ? bs[tid] * m : 0.0f;
        const float beta = block_reduce_bcast(bm, red);   // b^T G b
        const float ctc = beta / (gamma * gamma);

        __syncthreads();
        if (tid < D) {
            const float bd = bs[tid];
            bs[tid] = bd * (m / gamma) / (bd * ctc + EPS);  // exact EPS in bases update
        }
        __syncthreads();
    }

    float v = (tid < D) ? bs[tid] * bs[tid] : 0.0f;
    const float btb = block_reduce_bcast(v, red);
    const float inv = 1.0f / (btb + EPS);
    if (tid < D) {
        bvec[batch * D + tid] = bs[tid];
        svec[batch * D + tid] = bs[tid] * inv;
    }
}

// ---------------- Kernel C: out[d,n] = s[d] * (x^T b)[n]  (rank-1, no LDS) ------
// Each thread owns ONE float4 of n: private t4 = sum_d b[d]*x[d,n4] (160 fully
// independent coalesced 1KB/wave loads), then 160 coalesced NT stores.
// No LDS round-trip, no syncs, no serial reduce phase. b/s are uniform s_loads.
// 64-thread blocks, grid (324,4) = 1296 blocks -> fine-grained CU backfill.
__global__ __launch_bounds__(64)
void out_kernel(const float* __restrict__ x, const float* __restrict__ bvec,
                const float* __restrict__ svec, float* __restrict__ out)
{
    const int batch = blockIdx.y;
    const size_t base = (size_t)batch * D * NN + (size_t)blockIdx.x * 256
                      + ((size_t)threadIdx.x << 2);
    const float* bb = bvec + batch * D;
    const float* ss = svec + batch * D;

    floatx4 t = {0.f, 0.f, 0.f, 0.f};
    #pragma unroll 8
    for (int d = 0; d < D; ++d)
        t += *(const floatx4*)(x + base + (size_t)d * NN) * bb[d];

    #pragma unroll 8
    for (int d = 0; d < D; ++d)
        __builtin_nontemporal_store(t * ss[d], (floatx4*)(out + base + (size_t)d * NN));
}

extern "C" void kernel_launch(void* const* d_in, const int* in_sizes, int n_in,
                              void* d_out, int out_size, void* d_ws, size_t ws_size,
                              hipStream_t stream)
{
    (void)in_sizes; (void)n_in; (void)out_size; (void)ws_size;
    const float* x     = (const float*)d_in[0];
    const float* bases = (const float*)d_in[1];
    float* out = (float*)d_out;

    // Scratch layout inside d_out (fully overwritten by out_kernel at the end):
    //   P: partial Gram tiles, 4*81*25600 floats = 33.2 MB at offset 0
    //   G: reduced Gram, 102,400 floats at float-offset 50,000,000 (200 MB; 16B-aligned)
    // d_out total = 4*16*160*72*72 = 53,084,160 floats -> both fit, no overlap.
    float* P    = (float*)d_out;
    float* G    = (float*)d_out + (size_t)50000000;
    float* bvec = (float*)d_ws;          // 4*160 floats
    float* svec = bvec + B * D;          // 4*160 floats

    gram_kernel<<<dim3(GRAM_BLOCKS, B), 256, 0, stream>>>(x, P);
    reduce_kernel<<<dim3(25, B), 256, 0, stream>>>(P, G);
    iter_kernel<<<dim3(B), 256, 0, stream>>>(bases, G, bvec, svec);
    out_kernel<<<dim3(NN / 256, B), 64, 0, stream>>>(x, bvec, svec, out);
}